// Round 8
// baseline (225.877 us; speedup 1.0000x reference)
//
#include <hip/hip_runtime.h>

typedef __attribute__((ext_vector_type(4))) float f32x4;
typedef __attribute__((ext_vector_type(8))) short bf16x8;

#define BN_EPS 1e-5f
constexpr int BATCH = 32;

static inline int cdiv(int a, int b) { return (a + b - 1) / b; }

__device__ __forceinline__ float lrelu(float v) { return v > 0.f ? v : 0.1f * v; }

// f32 -> bf16 round-to-nearest-even
__device__ __forceinline__ unsigned short f2bf(float f) {
    unsigned u = __float_as_uint(f);
    u = (u + 0x7FFFu + ((u >> 16) & 1u)) >> 16;
    return (unsigned short)u;
}

// LDS XOR swizzle (elem units, preserves 16B granules): breaks the 64B-lane-stride
// 8-way bank conflict on ds_read_b128 fragment loads down to ~2-way (free).
#define SWZ(e) ((e) ^ ((((e) >> 6) & 3) << 3))

// ---------------------------------------------------------------------------
// Weight prep (one launch): decoder convs -> [tap][COUT][CINP] bf16 (Cin pad),
// encoder conv2 -> [13][32][32] dual-tap slots, encoder conv3 -> [9][32][32].
// ---------------------------------------------------------------------------
__global__ void prep_w_all(const float* w1, const float* w2, const float* w3, const float* w4,
                           const float* wE2s, const float* wE3s,
                           unsigned short* d1, unsigned short* d2, unsigned short* d3,
                           unsigned short* d4, unsigned short* dE2, unsigned short* dE3)
{
    int idx = blockIdx.x * blockDim.x + threadIdx.x;
    if (idx < 368640) {
        const float* src; unsigned short* dst; int COUT, CINS, CINP;
        if (idx < 221184)      { src = w1; dst = d1; COUT = 128; CINS = 169; CINP = 192; }
        else if (idx < 294912) { src = w2; dst = d2; COUT = 64;  CINS = 128; CINP = 128; idx -= 221184; }
        else if (idx < 350208) { src = w3; dst = d3; COUT = 64;  CINS = 96;  CINP = 96;  idx -= 294912; }
        else                   { src = w4; dst = d4; COUT = 32;  CINS = 64;  CINP = 64;  idx -= 350208; }
        int ic  = idx % CINP;
        int oc  = (idx / CINP) % COUT;
        int tap = idx / (CINP * COUT);
        float v = (ic < CINS) ? src[((size_t)oc * CINS + ic) * 9 + tap] : 0.f;
        dst[((size_t)tap * COUT + oc) * CINP + ic] = f2bf(v);
    } else if (idx < 381952) {               // encoder conv2: [13][32 oc][32 k]
        idx -= 368640;
        int c = idx % 32, oc = (idx / 32) % 32, s = idx / 1024;
        int tap = 2 * s + (c >= 16 ? 1 : 0);
        int ic = c & 15;
        float v = (tap < 25) ? wE2s[((size_t)oc * 16 + ic) * 25 + tap] : 0.f;
        dE2[idx] = f2bf(v);
    } else if (idx < 391168) {               // encoder conv3: [9][32][32]
        idx -= 381952;
        int ic = idx % 32, oc = (idx / 32) % 32, tap = idx / 1024;
        dE3[idx] = f2bf(wE3s[((size_t)oc * 32 + ic) * 9 + tap]);
    }
}

// ---------------------------------------------------------------------------
// MFMA implicit-GEMM 3x3 pad-1 conv, NHWC bf16 in, fp32 accum.
// WM=4 path (MB=64, TH=16): 16 MFMA per 8 ds_reads per tap (0.5 reads/MFMA).
// OM=0: bf16 out + lrelu.  OM=1: f32 out, no activation (pre-BN).
// MODE 1 (f1): ch0-63 = upsample2x(d2), 64-95 = fineA/fineB skip.
// ---------------------------------------------------------------------------
template<int CIN, int COUT, int H, int TH, int MODE, int OM>
__global__ __launch_bounds__(256) void conv3x3_mfma(
    const unsigned short* __restrict__ in,
    const unsigned short* __restrict__ in2,
    const unsigned short* __restrict__ wT,   // [9][COUT][CIN] bf16
    const float* __restrict__ bias,
    unsigned short* __restrict__ out)
{
    constexpr int MB = (COUT >= 64) ? 64 : COUT;
    constexpr int MFRAGS = MB / 16;
    constexpr int WM = (MFRAGS == 4 && TH >= 16) ? 4 : 2;
    constexpr int MW = MFRAGS / WM;
    constexpr int NW = 4 / MW;
    constexpr int WN = TH / NW;

    __shared__ unsigned short s_w[9 * MB * 32];
    __shared__ unsigned short s_in[(TH + 2) * 18 * 32];

    const int tid  = threadIdx.x;
    const int wid  = tid >> 6;
    const int lane = tid & 63;
    const int l15  = lane & 15;
    const int kg   = lane >> 4;
    constexpr int TILESX = H / 16;
    const int bx = blockIdx.x;
    const int x0 = (bx % TILESX) * 16;
    const int y0 = (bx / TILESX) * TH;
    const int ocbase = blockIdx.y * MB;
    const int n = blockIdx.z;

    const int mw = wid % MW;
    const int nw = wid / MW;

    f32x4 acc[WM][WN];
    #pragma unroll
    for (int i = 0; i < WM; ++i) {
        #pragma unroll
        for (int r = 0; r < 4; ++r) {
            float bv = bias[ocbase + (mw * WM + i) * 16 + kg * 4 + r];
            #pragma unroll
            for (int j = 0; j < WN; ++j) acc[i][j][r] = bv;
        }
    }

    for (int c0 = 0; c0 < CIN; c0 += 32) {
        for (int t = tid; t < 9 * MB * 4; t += 256) {
            int sub = t & 3;
            int row = t >> 2;
            int tap = row / MB, oc = row % MB;
            const unsigned short* src = wT + ((size_t)(tap * COUT + ocbase + oc) * CIN + c0) + sub * 8;
            *(int4*)&s_w[SWZ(row * 32 + sub * 8)] = *(const int4*)src;
        }
        for (int t = tid; t < (TH + 2) * 18 * 4; t += 256) {
            int sub = t & 3;
            int p = t >> 2;
            int y = p / 18, x = p - y * 18;
            int gy = y0 - 1 + y, gx = x0 - 1 + x;
            int4 v = {0, 0, 0, 0};
            if ((unsigned)gy < (unsigned)H && (unsigned)gx < (unsigned)H) {
                if (MODE == 0) {
                    v = *(const int4*)&in[((size_t)(n * H + gy) * H + gx) * CIN + c0 + sub * 8];
                } else {
                    if (c0 < 64) {
                        v = *(const int4*)&in[((size_t)(n * 32 + (gy >> 1)) * 32 + (gx >> 1)) * 64 + c0 + sub * 8];
                    } else {
                        int f  = sub >> 1;
                        int cc = (sub & 1) * 8;
                        v = *(const int4*)&in2[((size_t)((f * BATCH + n) * 64 + gy) * 64 + gx) * 16 + cc];
                    }
                }
            }
            *(int4*)&s_in[SWZ(p * 32 + sub * 8)] = v;
        }
        __syncthreads();

        #pragma unroll
        for (int tap = 0; tap < 9; ++tap) {
            const int kh = tap / 3, kw = tap - (tap / 3) * 3;
            bf16x8 a[WM], b[WN];
            #pragma unroll
            for (int i = 0; i < WM; ++i) {
                int mf = mw * WM + i;
                a[i] = *(const bf16x8*)&s_w[SWZ((tap * MB + mf * 16 + l15) * 32 + kg * 8)];
            }
            #pragma unroll
            for (int j = 0; j < WN; ++j) {
                int nf = nw * WN + j;
                b[j] = *(const bf16x8*)&s_in[SWZ(((nf + kh) * 18 + l15 + kw) * 32 + kg * 8)];
            }
            #pragma unroll
            for (int i = 0; i < WM; ++i)
                #pragma unroll
                for (int j = 0; j < WN; ++j)
                    acc[i][j] = __builtin_amdgcn_mfma_f32_16x16x32_bf16(a[i], b[j], acc[i][j], 0, 0, 0);
        }
        __syncthreads();
    }

    #pragma unroll
    for (int i = 0; i < WM; ++i) {
        int oc = ocbase + (mw * WM + i) * 16 + kg * 4;
        #pragma unroll
        for (int j = 0; j < WN; ++j) {
            int nf = nw * WN + j;
            int gy = y0 + nf, gx = x0 + l15;
            size_t base = ((size_t)(n * H + gy) * H + gx) * COUT + oc;
            if (OM == 0) {
                ushort4 pk;
                pk.x = f2bf(lrelu(acc[i][j][0]));
                pk.y = f2bf(lrelu(acc[i][j][1]));
                pk.z = f2bf(lrelu(acc[i][j][2]));
                pk.w = f2bf(lrelu(acc[i][j][3]));
                *(ushort4*)&out[base] = pk;
            } else {
                *(f32x4*)&((float*)out)[base] = acc[i][j];
            }
        }
    }
}

// ---------------------------------------------------------------------------
// Encoder conv2 (MFMA): 5x5 stride2 pad2, 16->32ch, 64->32. In: fineN bf16
// NHWC [64][64][64][16]. Out: f32 NHWC [64][32][32][32]. K=32 packs 2 taps.
// ---------------------------------------------------------------------------
__global__ __launch_bounds__(256) void conv2s_mfma(
    const unsigned short* __restrict__ in, const unsigned short* __restrict__ wS,
    const float* __restrict__ bias, float* __restrict__ out)
{
    __shared__ unsigned short s_w[13 * 32 * 32];     // [slot][oc32][k32]
    __shared__ unsigned short s_in[20 * 36 * 16];    // [y][x][16ch]

    const int tid = threadIdx.x;
    const int nw  = tid >> 6;                        // wave = N split (4)
    const int lane = tid & 63;
    const int l15 = lane & 15;
    const int kg  = lane >> 4;
    const int x0 = (blockIdx.x & 1) * 16;            // out col base
    const int y0 = (blockIdx.x >> 1) * 8;            // out row base
    const int n  = blockIdx.z;

    f32x4 acc[2][2];
    #pragma unroll
    for (int i = 0; i < 2; ++i) {
        #pragma unroll
        for (int r = 0; r < 4; ++r) {
            float bv = bias[i * 16 + kg * 4 + r];
            acc[i][0][r] = bv; acc[i][1][r] = bv;
        }
    }

    for (int t = tid; t < 1664; t += 256) {          // 13*32 rows * 4 subs
        int sub = t & 3, row = t >> 2;
        *(int4*)&s_w[SWZ(row * 32 + sub * 8)] = *(const int4*)&wS[row * 32 + sub * 8];
    }
    for (int t = tid; t < 1440; t += 256) {          // 20*36 px * 2 subs
        int sub = t & 1, p = t >> 1;
        int y = p / 36, x = p - y * 36;
        int gy = 2 * y0 - 2 + y, gx = 2 * x0 - 2 + x;
        int4 v = {0, 0, 0, 0};
        if ((unsigned)gy < 64u && (unsigned)gx < 64u)
            v = *(const int4*)&in[((size_t)(n * 64 + gy) * 64 + gx) * 16 + sub * 8];
        *(int4*)&s_in[SWZ((y * 36 + x) * 16 + sub * 8)] = v;
    }
    __syncthreads();

    #pragma unroll
    for (int s = 0; s < 13; ++s) {
        int tA = 2 * s, tB = 2 * s + 1;              // tB==25 -> zero weights
        int khA = tA / 5, kwA = tA % 5;
        int khB = tB / 5, kwB = tB % 5;
        int kh = (kg < 2) ? khA : khB;
        int kw = (kg < 2) ? kwA : kwB;
        int co = (kg & 1) * 8;
        bf16x8 a[2], b[2];
        a[0] = *(const bf16x8*)&s_w[SWZ((s * 32 + l15) * 32 + kg * 8)];
        a[1] = *(const bf16x8*)&s_w[SWZ((s * 32 + 16 + l15) * 32 + kg * 8)];
        #pragma unroll
        for (int j = 0; j < 2; ++j) {
            int py = nw * 2 + j;
            b[j] = *(const bf16x8*)&s_in[SWZ(((2 * py + kh) * 36 + 2 * l15 + kw) * 16 + co)];
        }
        acc[0][0] = __builtin_amdgcn_mfma_f32_16x16x32_bf16(a[0], b[0], acc[0][0], 0, 0, 0);
        acc[0][1] = __builtin_amdgcn_mfma_f32_16x16x32_bf16(a[0], b[1], acc[0][1], 0, 0, 0);
        acc[1][0] = __builtin_amdgcn_mfma_f32_16x16x32_bf16(a[1], b[0], acc[1][0], 0, 0, 0);
        acc[1][1] = __builtin_amdgcn_mfma_f32_16x16x32_bf16(a[1], b[1], acc[1][1], 0, 0, 0);
    }

    #pragma unroll
    for (int i = 0; i < 2; ++i)
        #pragma unroll
        for (int j = 0; j < 2; ++j) {
            int gy = y0 + nw * 2 + j, gx = x0 + l15;
            *(f32x4*)&out[((size_t)(n * 32 + gy) * 32 + gx) * 32 + i * 16 + kg * 4] = acc[i][j];
        }
}

// ---------------------------------------------------------------------------
// Encoder conv1: 7x7 pad3, Cin=1, Cout=16, both frames. Out NHWC f32 [64][4096][16].
// ---------------------------------------------------------------------------
__global__ __launch_bounds__(256) void conv1_tiled(
    const float* __restrict__ fA, const float* __restrict__ fB,
    const float* __restrict__ w, const float* __restrict__ bias,
    float* __restrict__ out)
{
    __shared__ float s_in[38][40];
    __shared__ float s_w[49][8];

    const int tid = threadIdx.x;
    const int tx = tid & 15, ty = tid >> 4;
    const int tile = blockIdx.x;
    const int x0 = (tile & 1) << 5;
    const int y0 = (tile >> 1) << 5;
    const int ocbase = blockIdx.y * 8;
    const int n = blockIdx.z;
    const float* in = (n < BATCH) ? (fA + (size_t)n * 4096) : (fB + (size_t)(n - BATCH) * 4096);

    for (int t = tid; t < 49 * 8; t += 256) {
        int oc = t & 7, k = t >> 3;
        s_w[k][oc] = w[(ocbase + oc) * 49 + k];
    }
    for (int t = tid; t < 38 * 38; t += 256) {
        int y = t / 38, x = t - (t / 38) * 38;
        int gy = y0 + y - 3, gx = x0 + x - 3;
        float v = 0.f;
        if ((unsigned)gy < 64u && (unsigned)gx < 64u) v = in[gy * 64 + gx];
        s_in[y][x] = v;
    }
    __syncthreads();

    float acc[8][4];
    #pragma unroll
    for (int oc = 0; oc < 8; ++oc) {
        float bv = bias[ocbase + oc];
        acc[oc][0] = bv; acc[oc][1] = bv; acc[oc][2] = bv; acc[oc][3] = bv;
    }
    #pragma unroll
    for (int kh = 0; kh < 7; ++kh) {
        #pragma unroll
        for (int kw = 0; kw < 7; ++kw) {
            float i00 = s_in[ty + kh][tx + kw];
            float i01 = s_in[ty + kh][tx + 16 + kw];
            float i10 = s_in[ty + 16 + kh][tx + kw];
            float i11 = s_in[ty + 16 + kh][tx + 16 + kw];
            #pragma unroll
            for (int oc = 0; oc < 8; ++oc) {
                float wv = s_w[kh * 7 + kw][oc];
                acc[oc][0] = fmaf(i00, wv, acc[oc][0]);
                acc[oc][1] = fmaf(i01, wv, acc[oc][1]);
                acc[oc][2] = fmaf(i10, wv, acc[oc][2]);
                acc[oc][3] = fmaf(i11, wv, acc[oc][3]);
            }
        }
    }
    #pragma unroll
    for (int i = 0; i < 2; ++i)
        #pragma unroll
        for (int j = 0; j < 2; ++j) {
            int oy = y0 + ty + i * 16, ox = x0 + tx + j * 16;
            float4 v0 = {acc[0][i * 2 + j], acc[1][i * 2 + j], acc[2][i * 2 + j], acc[3][i * 2 + j]};
            float4 v1 = {acc[4][i * 2 + j], acc[5][i * 2 + j], acc[6][i * 2 + j], acc[7][i * 2 + j]};
            float* dst = out + ((size_t)n * 4096 + oy * 64 + ox) * 16 + ocbase;
            *(float4*)dst = v0;
            *(float4*)(dst + 4) = v1;
        }
}

// ---------------------------------------------------------------------------
// BN stats stage 1 on NHWC f32 (coalesced partials). NS=128 slices per frame set.
// ---------------------------------------------------------------------------
template<int C, int NS>
__global__ void bn_part_nhwc(const float* __restrict__ x, float2* __restrict__ part, int HW)
{
    constexpr int G = 256 / C;
    int f = blockIdx.x / NS, s = blockIdx.x % NS;
    int RS = (32 * HW) / NS;
    const float* base = x + ((size_t)f * 32 * HW + (size_t)s * RS) * C;
    int c = threadIdx.x % C, rg = threadIdx.x / C;
    float s1 = 0.f, s2 = 0.f;
    for (int r = rg; r < RS; r += G) {
        float v = base[(size_t)r * C + c];
        s1 += v; s2 += v * v;
    }
    __shared__ float2 sh[256];
    sh[threadIdx.x] = make_float2(s1, s2);
    __syncthreads();
    for (int off = 128; off >= C; off >>= 1) {
        if (threadIdx.x < off) {
            float2 o = sh[threadIdx.x + off];
            sh[threadIdx.x].x += o.x; sh[threadIdx.x].y += o.y;
        }
        __syncthreads();
    }
    if (threadIdx.x < C) part[(size_t)(f * C + c) * NS + s] = sh[threadIdx.x];
}

// Per-block finalize of stage-1 partials into LDS stats (mean, rsqrt).
// All 256 threads participate; block's frame index f must be uniform.
template<int C>
__device__ __forceinline__ void finalize_stats(const float2* __restrict__ part, int f,
                                               float inv, float* sstats)
{
    __shared__ float2 red[256];
    int t = threadIdx.x;
    int c = t % C, k = t / C;
    float s1 = 0.f, s2 = 0.f;
    for (int q = k; q < 128; q += 256 / C) {
        float2 p = part[(size_t)(f * C + c) * 128 + q];
        s1 += p.x; s2 += p.y;
    }
    red[t] = make_float2(s1, s2);
    __syncthreads();
    for (int off = 128; off >= C; off >>= 1) {
        if (t < off) { red[t].x += red[t + off].x; red[t].y += red[t + off].y; }
        __syncthreads();
    }
    if (t < C) {
        float m = red[t].x * inv;
        float var = red[t].y * inv - m * m;
        sstats[2 * t]     = m;
        sstats[2 * t + 1] = rsqrtf(var + BN_EPS);
    }
    __syncthreads();
}

// BN1 finalize+apply: NHWC f32 [64][4096][16] -> NHWC bf16 (lrelu). Grid exactly 1024.
__global__ __launch_bounds__(256) void bn1_apply(const float* __restrict__ xN,
                          const float2* __restrict__ part,
                          const float* __restrict__ g, const float* __restrict__ be,
                          unsigned short* __restrict__ outN)
{
    __shared__ float sst[32];
    int idx = blockIdx.x * blockDim.x + threadIdx.x;
    int f = idx >> 17;
    finalize_stats<16>(part, f, 1.f / (32.f * 4096.f), sst);
    const float* src = xN + (size_t)idx * 16;
    unsigned short o[16];
    #pragma unroll
    for (int c = 0; c < 16; ++c)
        o[c] = f2bf(lrelu((src[c] - sst[2 * c]) * sst[2 * c + 1] * g[c] + be[c]));
    int4* dst = (int4*)(outN + (size_t)idx * 16);
    dst[0] = *(int4*)&o[0];
    dst[1] = *(int4*)&o[8];
}

// BN2 finalize+apply: NHWC f32 [64][1024][32] -> NHWC bf16 (lrelu). Grid exactly 256.
__global__ __launch_bounds__(256) void bn2_apply(const float* __restrict__ xN,
                          const float2* __restrict__ part,
                          const float* __restrict__ g, const float* __restrict__ be,
                          unsigned short* __restrict__ outN)
{
    __shared__ float sst[64];
    int idx = blockIdx.x * blockDim.x + threadIdx.x;
    int f = idx >> 15;
    finalize_stats<32>(part, f, 1.f / (32.f * 1024.f), sst);
    const float* src = xN + (size_t)idx * 32;
    unsigned short o[32];
    #pragma unroll
    for (int c = 0; c < 32; ++c)
        o[c] = f2bf(lrelu((src[c] - sst[2 * c]) * sst[2 * c + 1] * g[c] + be[c]));
    int4* dst = (int4*)(outN + (size_t)idx * 32);
    #pragma unroll
    for (int q = 0; q < 4; ++q) dst[q] = *(int4*)&o[q * 8];
}

// BN3 finalize + lrelu + channel L2 norm: NHWC f32 -> NHWC f32. Grid exactly 256.
__global__ __launch_bounds__(256) void bn3_l2n_nhwc(const float* __restrict__ xN,
                             const float2* __restrict__ part,
                             const float* __restrict__ g, const float* __restrict__ be,
                             float* __restrict__ outN)
{
    __shared__ float sst[64];
    int idx = blockIdx.x * blockDim.x + threadIdx.x;
    int f = idx >> 15;
    finalize_stats<32>(part, f, 1.f / (32.f * 1024.f), sst);
    const float* src = xN + (size_t)idx * 32;
    float v[32];
    float ss = 0.f;
    #pragma unroll
    for (int c = 0; c < 32; ++c) {
        float t = lrelu((src[c] - sst[2 * c]) * sst[2 * c + 1] * g[c] + be[c]);
        v[c] = t; ss += t * t;
    }
    float inv = 1.f / fmaxf(sqrtf(ss), 1e-12f);
    float* dst = outN + (size_t)idx * 32;
    #pragma unroll
    for (int c = 0; c < 32; ++c) dst[c] = v[c] * inv;
}

// ---------------------------------------------------------------------------
// Correlation (LDS-tiled): coarseN NHWC f32 [64][1024][32] -> cost bf16
// [B][1024][192] (channels 169..191 untouched: decoder weights there are 0).
// ---------------------------------------------------------------------------
#define CSWZ(c, w) ((c) ^ (((w) & 7) << 2))

__global__ __launch_bounds__(256) void corr_tile(const float* __restrict__ xN,
                                                 unsigned short* __restrict__ cost)
{
    __shared__ float sA[32 * 32];
    __shared__ float sB[13][32 * 32];
    __shared__ unsigned short sC[32][176];

    const int h = blockIdx.x, b = blockIdx.y;
    const float* Ab = xN + ((size_t)b * 1024 + h * 32) * 32;
    const float* Bb = xN + ((size_t)(BATCH + b) * 1024) * 32;

    {   // stage A: 32 pos x 8 granules
        int t = threadIdx.x;
        int w = t >> 3, gr = t & 7;
        f32x4 v = *(const f32x4*)&Ab[w * 32 + gr * 4];
        *(f32x4*)&sA[w * 32 + CSWZ(gr * 4, w)] = v;
    }
    for (int t = threadIdx.x; t < 13 * 256; t += 256) {  // stage B rows h-6..h+6
        int row = t >> 8, q = t & 255;
        int w = q >> 3, gr = q & 7;
        int gh = h + row - 6;
        f32x4 v = {0.f, 0.f, 0.f, 0.f};
        if ((unsigned)gh < 32u) v = *(const f32x4*)&Bb[((size_t)gh * 32 + w) * 32 + gr * 4];
        *(f32x4*)&sB[row][w * 32 + CSWZ(gr * 4, w)] = v;
    }
    __syncthreads();

    const int w = threadIdx.x & 31;
    const int g = threadIdx.x >> 5;     // 0..7
    f32x4 a[8];
    #pragma unroll
    for (int gr = 0; gr < 8; ++gr) a[gr] = *(const f32x4*)&sA[w * 32 + CSWZ(gr * 4, w)];

    for (int dy = g; dy < 13; dy += 8) {
        #pragma unroll
        for (int dx = 0; dx < 13; ++dx) {
            int wb = w + dx - 6;
            float s = 0.f;
            if ((unsigned)wb < 32u) {
                #pragma unroll
                for (int gr = 0; gr < 8; ++gr) {
                    f32x4 bv = *(const f32x4*)&sB[dy][wb * 32 + CSWZ(gr * 4, wb)];
                    s += a[gr].x * bv.x + a[gr].y * bv.y + a[gr].z * bv.z + a[gr].w * bv.w;
                }
            }
            sC[w][dy * 13 + dx] = f2bf(s);
        }
    }
    __syncthreads();

    // coalesced copy-out: 32 pos x 169 d
    for (int t = threadIdx.x; t < 32 * 169; t += 256) {
        int ww = t / 169;
        int d  = t - ww * 169;
        cost[((size_t)(b * 1024) + h * 32 + ww) * 192 + d] = sC[ww][d];
    }
}

// ---------------------------------------------------------------------------
// Final 1x1 conv: f2o NHWC bf16 [B][4096][32] -> out NCHW f32 (B,2,64,64)
// ---------------------------------------------------------------------------
__global__ void conv_out_bf16(const unsigned short* __restrict__ x, const float* __restrict__ w,
                              const float* __restrict__ bias, float* __restrict__ out)
{
    int idx = blockIdx.x * blockDim.x + threadIdx.x;
    if (idx >= BATCH * 4096) return;
    const int4* xq = (const int4*)(x + (size_t)idx * 32);
    float s0 = bias[0], s1 = bias[1];
    #pragma unroll
    for (int q = 0; q < 4; ++q) {
        int4 vq = xq[q];
        int e[4] = {vq.x, vq.y, vq.z, vq.w};
        #pragma unroll
        for (int k = 0; k < 4; ++k) {
            int c = q * 8 + k * 2;
            float v0 = __uint_as_float(((unsigned)e[k]) << 16);
            float v1 = __uint_as_float(((unsigned)e[k]) & 0xFFFF0000u);
            s0 = fmaf(v0, w[c], s0);     s1 = fmaf(v0, w[32 + c], s1);
            s0 = fmaf(v1, w[c + 1], s0); s1 = fmaf(v1, w[32 + c + 1], s1);
        }
    }
    int n = idx >> 12, p = idx & 4095;
    out[((size_t)n * 2) * 4096 + p]     = s0;
    out[((size_t)n * 2 + 1) * 4096 + p] = s1;
}

// ---------------------------------------------------------------------------
extern "C" void kernel_launch(void* const* d_in, const int* in_sizes, int n_in,
                              void* d_out, int out_size, void* d_ws, size_t ws_size,
                              hipStream_t stream)
{
    const float* frameA = (const float*)d_in[0];
    const float* frameB = (const float*)d_in[1];
    const float* w1  = (const float*)d_in[2];
    const float* b1  = (const float*)d_in[3];
    const float* g1  = (const float*)d_in[4];
    const float* be1 = (const float*)d_in[5];
    const float* w2  = (const float*)d_in[6];
    const float* b2  = (const float*)d_in[7];
    const float* g2  = (const float*)d_in[8];
    const float* be2 = (const float*)d_in[9];
    const float* w3  = (const float*)d_in[10];
    const float* b3  = (const float*)d_in[11];
    const float* g3  = (const float*)d_in[12];
    const float* be3 = (const float*)d_in[13];
    const float* wc1 = (const float*)d_in[14];
    const float* bc1 = (const float*)d_in[15];
    const float* wc2 = (const float*)d_in[16];
    const float* bc2 = (const float*)d_in[17];
    const float* wf1 = (const float*)d_in[18];
    const float* bf1 = (const float*)d_in[19];
    const float* wf2 = (const float*)d_in[20];
    const float* bf2 = (const float*)d_in[21];
    const float* wo  = (const float*)d_in[22];
    const float* bo  = (const float*)d_in[23];

    // workspace layout
    float* ws      = (float*)d_ws;
    float* fine1N  = ws;                    // [64][4096][16] f32   4,194,304
    float* h2N     = fine1N + 4194304;      // [64][1024][32] f32   2,097,152
    float* c3N     = h2N + 2097152;         // [64][1024][32] f32   2,097,152
    float* coarseN = c3N + 2097152;         // [64][1024][32] f32   2,097,152
    float* stats   = coarseN + 2097152;     // 256 (unused, kept for layout)
    float2* part   = (float2*)(stats + 256);          // 16384 floats
    unsigned short* fineN = (unsigned short*)(stats + 256 + 16384);  // [64][64][64][16]
    unsigned short* h2bf  = fineN + 4194304;   // [64][32][32][32]  2,097,152
    unsigned short* costN = h2bf + 2097152;    // [B][32][32][192]  6,291,456
    unsigned short* d1    = costN + 6291456;   // [B][32][32][128]  4,194,304
    unsigned short* d2    = d1 + 4194304;      // [B][32][32][64]   2,097,152
    unsigned short* f1o   = d2 + 2097152;      // [B][64][64][64]   8,388,608
    unsigned short* f2o   = f1o + 8388608;     // [B][64][64][32]   4,194,304
    unsigned short* wT1   = f2o + 4194304;     // [9][128][192]       221,184
    unsigned short* wT2   = wT1 + 221184;      // [9][64][128]         73,728
    unsigned short* wTf1  = wT2 + 73728;       // [9][64][96]          55,296
    unsigned short* wTf2  = wTf1 + 55296;      // [9][32][64]          18,432
    unsigned short* wE2   = wTf2 + 18432;      // [13][32][32]         13,312
    unsigned short* wE3   = wE2 + 13312;       // [9][32][32]           9,216

    const int T = 256;

    // weight prep (single launch)
    prep_w_all<<<cdiv(391168, T), T, 0, stream>>>(wc1, wc2, wf1, wf2, w2, w3,
                                                  wT1, wT2, wTf1, wTf2, wE2, wE3);

    // encoder layer 1 (fp32 direct, NHWC out)
    conv1_tiled<<<dim3(4, 2, 2 * BATCH), T, 0, stream>>>(frameA, frameB, w1, b1, fine1N);
    bn_part_nhwc<16, 128><<<2 * 128, T, 0, stream>>>(fine1N, part, 4096);
    bn1_apply<<<1024, T, 0, stream>>>(fine1N, part, g1, be1, fineN);

    // encoder layer 2 (MFMA, stride-2)
    conv2s_mfma<<<dim3(8, 1, 64), T, 0, stream>>>(fineN, wE2, b2, h2N);
    bn_part_nhwc<32, 128><<<2 * 128, T, 0, stream>>>(h2N, part, 1024);
    bn2_apply<<<256, T, 0, stream>>>(h2N, part, g2, be2, h2bf);

    // encoder layer 3 (MFMA)
    conv3x3_mfma<32, 32, 32, 8, 0, 1><<<dim3(8, 1, 64), T, 0, stream>>>(
        h2bf, nullptr, wE3, b3, (unsigned short*)c3N);
    bn_part_nhwc<32, 128><<<2 * 128, T, 0, stream>>>(c3N, part, 1024);
    bn3_l2n_nhwc<<<256, T, 0, stream>>>(c3N, part, g3, be3, coarseN);

    // correlation (LDS-tiled) -> bf16 NHWC cost
    corr_tile<<<dim3(32, BATCH), T, 0, stream>>>(coarseN, costN);

    // decoder (bf16 MFMA) — dec1 & f1 use TH=16 (WM=4: 0.5 ds_reads/MFMA)
    conv3x3_mfma<192, 128, 32, 16, 0, 0><<<dim3(4, 2, BATCH), T, 0, stream>>>(costN, nullptr, wT1, bc1, d1);
    conv3x3_mfma<128, 64, 32, 8, 0, 0><<<dim3(8, 1, BATCH), T, 0, stream>>>(d1, nullptr, wT2, bc2, d2);
    conv3x3_mfma<96, 64, 64, 16, 1, 0><<<dim3(16, 1, BATCH), T, 0, stream>>>(d2, fineN, wTf1, bf1, f1o);
    conv3x3_mfma<64, 32, 64, 16, 0, 0><<<dim3(16, 1, BATCH), T, 0, stream>>>(f1o, nullptr, wTf2, bf2, f2o);

    conv_out_bf16<<<cdiv(BATCH * 4096, T), T, 0, stream>>>(f2o, wo, bo, (float*)d_out);
}

// Round 10
// 198.688 us; speedup vs baseline: 1.1368x; 1.1368x over previous
//
#include <hip/hip_runtime.h>

typedef __attribute__((ext_vector_type(4))) float f32x4;
typedef __attribute__((ext_vector_type(8))) short bf16x8;

#define BN_EPS 1e-5f
constexpr int BATCH = 32;

static inline int cdiv(int a, int b) { return (a + b - 1) / b; }

__device__ __forceinline__ float lrelu(float v) { return v > 0.f ? v : 0.1f * v; }

__device__ __forceinline__ unsigned short f2bf(float f) {
    unsigned u = __float_as_uint(f);
    u = (u + 0x7FFFu + ((u >> 16) & 1u)) >> 16;
    return (unsigned short)u;
}
__device__ __forceinline__ float bf2f(unsigned short s) {
    return __uint_as_float(((unsigned)s) << 16);
}

// LDS XOR swizzles (elem units, preserve store granules)
#define SWZ(e)  ((e) ^ ((((e) >> 6) & 3) << 3))
#define FSWZ(e) ((e) ^ ((((e) >> 5) & 7) << 2))

// ---------------------------------------------------------------------------
// Weight prep: decoder convs -> [tap][COUT][CINP] bf16, enc2 dual-tap, enc3.
// ---------------------------------------------------------------------------
__global__ void prep_w_all(const float* w1, const float* w2, const float* w3, const float* w4,
                           const float* wE2s, const float* wE3s,
                           unsigned short* d1, unsigned short* d2, unsigned short* d3,
                           unsigned short* d4, unsigned short* dE2, unsigned short* dE3)
{
    int idx = blockIdx.x * blockDim.x + threadIdx.x;
    if (idx < 368640) {
        const float* src; unsigned short* dst; int COUT, CINS, CINP;
        if (idx < 221184)      { src = w1; dst = d1; COUT = 128; CINS = 169; CINP = 192; }
        else if (idx < 294912) { src = w2; dst = d2; COUT = 64;  CINS = 128; CINP = 128; idx -= 221184; }
        else if (idx < 350208) { src = w3; dst = d3; COUT = 64;  CINS = 96;  CINP = 96;  idx -= 294912; }
        else                   { src = w4; dst = d4; COUT = 32;  CINS = 64;  CINP = 64;  idx -= 350208; }
        int ic  = idx % CINP;
        int oc  = (idx / CINP) % COUT;
        int tap = idx / (CINP * COUT);
        float v = (ic < CINS) ? src[((size_t)oc * CINS + ic) * 9 + tap] : 0.f;
        dst[((size_t)tap * COUT + oc) * CINP + ic] = f2bf(v);
    } else if (idx < 381952) {
        idx -= 368640;
        int c = idx % 32, oc = (idx / 32) % 32, s = idx / 1024;
        int tap = 2 * s + (c >= 16 ? 1 : 0);
        int ic = c & 15;
        float v = (tap < 25) ? wE2s[((size_t)oc * 16 + ic) * 25 + tap] : 0.f;
        dE2[idx] = f2bf(v);
    } else if (idx < 391168) {
        idx -= 381952;
        int ic = idx % 32, oc = (idx / 32) % 32, tap = idx / 1024;
        dE3[idx] = f2bf(wE3s[((size_t)oc * 32 + ic) * 9 + tap]);
    }
}

// ---------------------------------------------------------------------------
// MFMA implicit-GEMM 3x3 pad-1 conv, NHWC bf16 in, fp32 accum.
// OM=0: bf16 out + lrelu. OM=1: f32 out, no act. OM=2: lrelu + fused 1x1 conv
// (32->2) through LDS, writes dout NCHW directly (requires MB=32, TH=16).
// MODE 1 (f1): ch0-63 = upsample2x(d2), 64-95 = fineA/fineB skip.
// ---------------------------------------------------------------------------
template<int CIN, int COUT, int H, int TH, int MODE, int OM>
__global__ __launch_bounds__(256) void conv3x3_mfma(
    const unsigned short* __restrict__ in,
    const unsigned short* __restrict__ in2,
    const unsigned short* __restrict__ wT,
    const float* __restrict__ bias,
    unsigned short* __restrict__ out,
    float* __restrict__ dout,
    const float* __restrict__ w1x1,
    const float* __restrict__ b1x1)
{
    constexpr int MB = (COUT >= 64) ? 64 : COUT;
    constexpr int MFRAGS = MB / 16;
    constexpr int WM = 2;
    constexpr int MW = MFRAGS / WM;
    constexpr int NW = 4 / MW;
    constexpr int WN = TH / NW;

    __shared__ unsigned short s_w[9 * MB * 32];
    __shared__ unsigned short s_in[(TH + 2) * 18 * 32];

    const int tid  = threadIdx.x;
    const int wid  = tid >> 6;
    const int lane = tid & 63;
    const int l15  = lane & 15;
    const int kg   = lane >> 4;
    constexpr int TILESX = H / 16;
    const int bx = blockIdx.x;
    const int x0 = (bx % TILESX) * 16;
    const int y0 = (bx / TILESX) * TH;
    const int ocbase = blockIdx.y * MB;
    const int n = blockIdx.z;

    const int mw = wid % MW;
    const int nw = wid / MW;

    f32x4 acc[WM][WN];
    #pragma unroll
    for (int i = 0; i < WM; ++i) {
        #pragma unroll
        for (int r = 0; r < 4; ++r) {
            float bv = bias[ocbase + (mw * WM + i) * 16 + kg * 4 + r];
            #pragma unroll
            for (int j = 0; j < WN; ++j) acc[i][j][r] = bv;
        }
    }

    for (int c0 = 0; c0 < CIN; c0 += 32) {
        for (int t = tid; t < 9 * MB * 4; t += 256) {
            int sub = t & 3;
            int row = t >> 2;
            int tap = row / MB, oc = row % MB;
            const unsigned short* src = wT + ((size_t)(tap * COUT + ocbase + oc) * CIN + c0) + sub * 8;
            *(int4*)&s_w[SWZ(row * 32 + sub * 8)] = *(const int4*)src;
        }
        for (int t = tid; t < (TH + 2) * 18 * 4; t += 256) {
            int sub = t & 3;
            int p = t >> 2;
            int y = p / 18, x = p - y * 18;
            int gy = y0 - 1 + y, gx = x0 - 1 + x;
            int4 v = {0, 0, 0, 0};
            if ((unsigned)gy < (unsigned)H && (unsigned)gx < (unsigned)H) {
                if (MODE == 0) {
                    v = *(const int4*)&in[((size_t)(n * H + gy) * H + gx) * CIN + c0 + sub * 8];
                } else {
                    if (c0 < 64) {
                        v = *(const int4*)&in[((size_t)(n * 32 + (gy >> 1)) * 32 + (gx >> 1)) * 64 + c0 + sub * 8];
                    } else {
                        int f  = sub >> 1;
                        int cc = (sub & 1) * 8;
                        v = *(const int4*)&in2[((size_t)((f * BATCH + n) * 64 + gy) * 64 + gx) * 16 + cc];
                    }
                }
            }
            *(int4*)&s_in[SWZ(p * 32 + sub * 8)] = v;
        }
        __syncthreads();

        #pragma unroll
        for (int tap = 0; tap < 9; ++tap) {
            const int kh = tap / 3, kw = tap - (tap / 3) * 3;
            bf16x8 a[WM], b[WN];
            #pragma unroll
            for (int i = 0; i < WM; ++i) {
                int mf = mw * WM + i;
                a[i] = *(const bf16x8*)&s_w[SWZ((tap * MB + mf * 16 + l15) * 32 + kg * 8)];
            }
            #pragma unroll
            for (int j = 0; j < WN; ++j) {
                int nf = nw * WN + j;
                b[j] = *(const bf16x8*)&s_in[SWZ(((nf + kh) * 18 + l15 + kw) * 32 + kg * 8)];
            }
            #pragma unroll
            for (int i = 0; i < WM; ++i)
                #pragma unroll
                for (int j = 0; j < WN; ++j)
                    acc[i][j] = __builtin_amdgcn_mfma_f32_16x16x32_bf16(a[i], b[j], acc[i][j], 0, 0, 0);
        }
        __syncthreads();
    }

    if constexpr (OM == 2) {
        // f2 + fused 1x1 output conv. MB=32, TH=16 -> block = 256 positions.
        __shared__ unsigned short sC[16 * 16 * 32];
        #pragma unroll
        for (int i = 0; i < WM; ++i) {
            #pragma unroll
            for (int j = 0; j < WN; ++j) {
                int pos = (nw * WN + j) * 16 + l15;
                int e = pos * 32 + (mw * WM + i) * 16 + kg * 4;
                ushort4 pk;
                pk.x = f2bf(lrelu(acc[i][j][0]));
                pk.y = f2bf(lrelu(acc[i][j][1]));
                pk.z = f2bf(lrelu(acc[i][j][2]));
                pk.w = f2bf(lrelu(acc[i][j][3]));
                *(ushort4*)&sC[FSWZ(e)] = pk;
            }
        }
        __syncthreads();
        float a0 = b1x1[0], a1 = b1x1[1];
        #pragma unroll
        for (int q = 0; q < 8; ++q) {
            int e = tid * 32 + q * 4;
            ushort4 v = *(const ushort4*)&sC[FSWZ(e)];
            int c = q * 4;
            float x0v = bf2f(v.x), x1v = bf2f(v.y), x2v = bf2f(v.z), x3v = bf2f(v.w);
            a0 = fmaf(x0v, w1x1[c], a0);     a1 = fmaf(x0v, w1x1[32 + c], a1);
            a0 = fmaf(x1v, w1x1[c + 1], a0); a1 = fmaf(x1v, w1x1[32 + c + 1], a1);
            a0 = fmaf(x2v, w1x1[c + 2], a0); a1 = fmaf(x2v, w1x1[32 + c + 2], a1);
            a0 = fmaf(x3v, w1x1[c + 3], a0); a1 = fmaf(x3v, w1x1[32 + c + 3], a1);
        }
        int row = tid >> 4, col = tid & 15;
        int gy = y0 + row, gx = x0 + col;
        dout[((size_t)n * 2) * 4096 + gy * 64 + gx]     = a0;
        dout[((size_t)n * 2 + 1) * 4096 + gy * 64 + gx] = a1;
    } else {
        #pragma unroll
        for (int i = 0; i < WM; ++i) {
            int oc = ocbase + (mw * WM + i) * 16 + kg * 4;
            #pragma unroll
            for (int j = 0; j < WN; ++j) {
                int nf = nw * WN + j;
                int gy = y0 + nf, gx = x0 + l15;
                size_t base = ((size_t)(n * H + gy) * H + gx) * COUT + oc;
                if (OM == 0) {
                    ushort4 pk;
                    pk.x = f2bf(lrelu(acc[i][j][0]));
                    pk.y = f2bf(lrelu(acc[i][j][1]));
                    pk.z = f2bf(lrelu(acc[i][j][2]));
                    pk.w = f2bf(lrelu(acc[i][j][3]));
                    *(ushort4*)&out[base] = pk;
                } else {
                    *(f32x4*)&((float*)out)[base] = acc[i][j];
                }
            }
        }
    }
}

// ---------------------------------------------------------------------------
// Encoder conv2 (MFMA): 5x5 s2 pad2, 16->32. In: fineN bf16 (post-BN1).
// Out: bf16 NHWC (pre-BN) + deterministic BN partials (slot = bx*32 + n%32).
// ---------------------------------------------------------------------------
__global__ __launch_bounds__(256) void conv2s_mfma(
    const unsigned short* __restrict__ in, const unsigned short* __restrict__ wS,
    const float* __restrict__ bias, unsigned short* __restrict__ outN,
    float2* __restrict__ part)
{
    __shared__ unsigned short s_w[13 * 32 * 32];
    __shared__ unsigned short s_in[20 * 36 * 16];
    __shared__ float2 redC[4][4][8];

    const int tid = threadIdx.x;
    const int nw  = tid >> 6;
    const int lane = tid & 63;
    const int l15 = lane & 15;
    const int kg  = lane >> 4;
    const int x0 = (blockIdx.x & 1) * 16;
    const int y0 = (blockIdx.x >> 1) * 8;
    const int n  = blockIdx.z;

    f32x4 acc[2][2];
    #pragma unroll
    for (int i = 0; i < 2; ++i) {
        #pragma unroll
        for (int r = 0; r < 4; ++r) {
            float bv = bias[i * 16 + kg * 4 + r];
            acc[i][0][r] = bv; acc[i][1][r] = bv;
        }
    }

    for (int t = tid; t < 1664; t += 256) {
        int sub = t & 3, row = t >> 2;
        *(int4*)&s_w[SWZ(row * 32 + sub * 8)] = *(const int4*)&wS[row * 32 + sub * 8];
    }
    for (int t = tid; t < 1440; t += 256) {
        int sub = t & 1, p = t >> 1;
        int y = p / 36, x = p - y * 36;
        int gy = 2 * y0 - 2 + y, gx = 2 * x0 - 2 + x;
        int4 v = {0, 0, 0, 0};
        if ((unsigned)gy < 64u && (unsigned)gx < 64u)
            v = *(const int4*)&in[((size_t)(n * 64 + gy) * 64 + gx) * 16 + sub * 8];
        *(int4*)&s_in[SWZ((y * 36 + x) * 16 + sub * 8)] = v;
    }
    __syncthreads();

    #pragma unroll
    for (int s = 0; s < 13; ++s) {
        int tA = 2 * s, tB = 2 * s + 1;
        int khA = tA / 5, kwA = tA % 5;
        int khB = tB / 5, kwB = tB % 5;
        int kh = (kg < 2) ? khA : khB;
        int kw = (kg < 2) ? kwA : kwB;
        int co = (kg & 1) * 8;
        bf16x8 a[2], b[2];
        a[0] = *(const bf16x8*)&s_w[SWZ((s * 32 + l15) * 32 + kg * 8)];
        a[1] = *(const bf16x8*)&s_w[SWZ((s * 32 + 16 + l15) * 32 + kg * 8)];
        #pragma unroll
        for (int j = 0; j < 2; ++j) {
            int py = nw * 2 + j;
            b[j] = *(const bf16x8*)&s_in[SWZ(((2 * py + kh) * 36 + 2 * l15 + kw) * 16 + co)];
        }
        acc[0][0] = __builtin_amdgcn_mfma_f32_16x16x32_bf16(a[0], b[0], acc[0][0], 0, 0, 0);
        acc[0][1] = __builtin_amdgcn_mfma_f32_16x16x32_bf16(a[0], b[1], acc[0][1], 0, 0, 0);
        acc[1][0] = __builtin_amdgcn_mfma_f32_16x16x32_bf16(a[1], b[0], acc[1][0], 0, 0, 0);
        acc[1][1] = __builtin_amdgcn_mfma_f32_16x16x32_bf16(a[1], b[1], acc[1][1], 0, 0, 0);
    }

    // bf16 store (pre-BN)
    #pragma unroll
    for (int i = 0; i < 2; ++i)
        #pragma unroll
        for (int j = 0; j < 2; ++j) {
            int gy = y0 + nw * 2 + j, gx = x0 + l15;
            ushort4 pk;
            pk.x = f2bf(acc[i][j][0]); pk.y = f2bf(acc[i][j][1]);
            pk.z = f2bf(acc[i][j][2]); pk.w = f2bf(acc[i][j][3]);
            *(ushort4*)&outN[((size_t)(n * 32 + gy) * 32 + gx) * 32 + i * 16 + kg * 4] = pk;
        }

    // BN partials (deterministic: shuffle + LDS tree)
    float t1[2][4], t2[2][4];
    #pragma unroll
    for (int i = 0; i < 2; ++i)
        #pragma unroll
        for (int r = 0; r < 4; ++r) {
            float v0 = acc[i][0][r], v1 = acc[i][1][r];
            t1[i][r] = v0 + v1;
            t2[i][r] = v0 * v0 + v1 * v1;
        }
    #pragma unroll
    for (int off = 8; off > 0; off >>= 1)
        #pragma unroll
        for (int i = 0; i < 2; ++i)
            #pragma unroll
            for (int r = 0; r < 4; ++r) {
                t1[i][r] += __shfl_down(t1[i][r], off);
                t2[i][r] += __shfl_down(t2[i][r], off);
            }
    if (l15 == 0) {
        #pragma unroll
        for (int i = 0; i < 2; ++i)
            #pragma unroll
            for (int r = 0; r < 4; ++r)
                redC[nw][kg][i * 4 + r] = make_float2(t1[i][r], t2[i][r]);
    }
    __syncthreads();
    if (tid < 32) {
        int oc = tid;
        int i = oc >> 4, kq = (oc & 15) >> 2, r = oc & 3;
        float2 s = redC[0][kq][i * 4 + r];
        #pragma unroll
        for (int w = 1; w < 4; ++w) {
            float2 p = redC[w][kq][i * 4 + r];
            s.x += p.x; s.y += p.y;
        }
        int f = n >> 5, slot = blockIdx.x * 32 + (n & 31);
        part[(size_t)(f * 32 + oc) * 256 + slot] = s;
    }
}

// ---------------------------------------------------------------------------
// Encoder conv1: 7x7 pad3, 1->16ch. Out bf16 NHWC (pre-BN) + BN partials.
// ---------------------------------------------------------------------------
__global__ __launch_bounds__(256) void conv1_tiled(
    const float* __restrict__ fA, const float* __restrict__ fB,
    const float* __restrict__ w, const float* __restrict__ bias,
    unsigned short* __restrict__ outN, float2* __restrict__ part)
{
    __shared__ float s_in[38][40];
    __shared__ float s_w[49][8];
    __shared__ float2 red1[4][8];

    const int tid = threadIdx.x;
    const int tx = tid & 15, ty = tid >> 4;
    const int tile = blockIdx.x;
    const int x0 = (tile & 1) << 5;
    const int y0 = (tile >> 1) << 5;
    const int ocbase = blockIdx.y * 8;
    const int n = blockIdx.z;
    const float* in = (n < BATCH) ? (fA + (size_t)n * 4096) : (fB + (size_t)(n - BATCH) * 4096);

    for (int t = tid; t < 49 * 8; t += 256) {
        int oc = t & 7, k = t >> 3;
        s_w[k][oc] = w[(ocbase + oc) * 49 + k];
    }
    for (int t = tid; t < 38 * 38; t += 256) {
        int y = t / 38, x = t - (t / 38) * 38;
        int gy = y0 + y - 3, gx = x0 + x - 3;
        float v = 0.f;
        if ((unsigned)gy < 64u && (unsigned)gx < 64u) v = in[gy * 64 + gx];
        s_in[y][x] = v;
    }
    __syncthreads();

    float acc[8][4];
    #pragma unroll
    for (int oc = 0; oc < 8; ++oc) {
        float bv = bias[ocbase + oc];
        acc[oc][0] = bv; acc[oc][1] = bv; acc[oc][2] = bv; acc[oc][3] = bv;
    }
    #pragma unroll
    for (int kh = 0; kh < 7; ++kh) {
        #pragma unroll
        for (int kw = 0; kw < 7; ++kw) {
            float i00 = s_in[ty + kh][tx + kw];
            float i01 = s_in[ty + kh][tx + 16 + kw];
            float i10 = s_in[ty + 16 + kh][tx + kw];
            float i11 = s_in[ty + 16 + kh][tx + 16 + kw];
            #pragma unroll
            for (int oc = 0; oc < 8; ++oc) {
                float wv = s_w[kh * 7 + kw][oc];
                acc[oc][0] = fmaf(i00, wv, acc[oc][0]);
                acc[oc][1] = fmaf(i01, wv, acc[oc][1]);
                acc[oc][2] = fmaf(i10, wv, acc[oc][2]);
                acc[oc][3] = fmaf(i11, wv, acc[oc][3]);
            }
        }
    }
    // bf16 NHWC store (pre-BN)
    #pragma unroll
    for (int i = 0; i < 2; ++i)
        #pragma unroll
        for (int j = 0; j < 2; ++j) {
            int k = i * 2 + j;
            int oy = y0 + ty + i * 16, ox = x0 + tx + j * 16;
            ushort4 p0, p1;
            p0.x = f2bf(acc[0][k]); p0.y = f2bf(acc[1][k]);
            p0.z = f2bf(acc[2][k]); p0.w = f2bf(acc[3][k]);
            p1.x = f2bf(acc[4][k]); p1.y = f2bf(acc[5][k]);
            p1.z = f2bf(acc[6][k]); p1.w = f2bf(acc[7][k]);
            unsigned short* dst = outN + ((size_t)n * 4096 + oy * 64 + ox) * 16 + ocbase;
            *(ushort4*)dst = p0;
            *(ushort4*)(dst + 4) = p1;
        }
    // BN partials
    float v1[8], v2[8];
    #pragma unroll
    for (int oc = 0; oc < 8; ++oc) {
        v1[oc] = acc[oc][0] + acc[oc][1] + acc[oc][2] + acc[oc][3];
        v2[oc] = acc[oc][0] * acc[oc][0] + acc[oc][1] * acc[oc][1]
               + acc[oc][2] * acc[oc][2] + acc[oc][3] * acc[oc][3];
    }
    #pragma unroll
    for (int off = 32; off > 0; off >>= 1)
        #pragma unroll
        for (int oc = 0; oc < 8; ++oc) {
            v1[oc] += __shfl_down(v1[oc], off);
            v2[oc] += __shfl_down(v2[oc], off);
        }
    int wid = tid >> 6, lane = tid & 63;
    if (lane == 0)
        #pragma unroll
        for (int oc = 0; oc < 8; ++oc) red1[wid][oc] = make_float2(v1[oc], v2[oc]);
    __syncthreads();
    if (tid < 8) {
        float2 s = red1[0][tid];
        #pragma unroll
        for (int w2_ = 1; w2_ < 4; ++w2_) { s.x += red1[w2_][tid].x; s.y += red1[w2_][tid].y; }
        int f = n >> 5, slot = blockIdx.x * 32 + (n & 31);
        part[(size_t)(f * 16 + ocbase + tid) * 128 + slot] = s;
    }
}

// ---------------------------------------------------------------------------
// BN stats stage 1 on NHWC f32 (only used for conv3 output now).
// ---------------------------------------------------------------------------
template<int C, int NS>
__global__ void bn_part_nhwc(const float* __restrict__ x, float2* __restrict__ part, int HW)
{
    constexpr int G = 256 / C;
    int f = blockIdx.x / NS, s = blockIdx.x % NS;
    int RS = (32 * HW) / NS;
    const float* base = x + ((size_t)f * 32 * HW + (size_t)s * RS) * C;
    int c = threadIdx.x % C, rg = threadIdx.x / C;
    float s1 = 0.f, s2 = 0.f;
    for (int r = rg; r < RS; r += G) {
        float v = base[(size_t)r * C + c];
        s1 += v; s2 += v * v;
    }
    __shared__ float2 sh[256];
    sh[threadIdx.x] = make_float2(s1, s2);
    __syncthreads();
    for (int off = 128; off >= C; off >>= 1) {
        if (threadIdx.x < off) {
            float2 o = sh[threadIdx.x + off];
            sh[threadIdx.x].x += o.x; sh[threadIdx.x].y += o.y;
        }
        __syncthreads();
    }
    if (threadIdx.x < C) part[(size_t)(f * C + c) * NS + s] = sh[threadIdx.x];
}

// Per-block finalize of stage-1 partials into LDS stats (mean, rsqrt).
template<int C, int NS>
__device__ __forceinline__ void finalize_stats(const float2* __restrict__ part, int f,
                                               float inv, float* sstats)
{
    __shared__ float2 red[256];
    int t = threadIdx.x;
    int c = t % C, k = t / C;
    float s1 = 0.f, s2 = 0.f;
    for (int q = k; q < NS; q += 256 / C) {
        float2 p = part[(size_t)(f * C + c) * NS + q];
        s1 += p.x; s2 += p.y;
    }
    red[t] = make_float2(s1, s2);
    __syncthreads();
    for (int off = 128; off >= C; off >>= 1) {
        if (t < off) { red[t].x += red[t + off].x; red[t].y += red[t + off].y; }
        __syncthreads();
    }
    if (t < C) {
        float m = red[t].x * inv;
        float var = red[t].y * inv - m * m;
        sstats[2 * t]     = m;
        sstats[2 * t + 1] = rsqrtf(var + BN_EPS);
    }
    __syncthreads();
}

// BN1 finalize+apply in-place on bf16 NHWC [64][4096][16]. Grid exactly 1024.
__global__ __launch_bounds__(256) void bn1_apply(unsigned short* __restrict__ xN,
                          const float2* __restrict__ part,
                          const float* __restrict__ g, const float* __restrict__ be)
{
    __shared__ float sst[32];
    int idx = blockIdx.x * blockDim.x + threadIdx.x;
    int f = idx >> 17;
    finalize_stats<16, 128>(part, f, 1.f / (32.f * 4096.f), sst);
    unsigned short* p = xN + (size_t)idx * 16;
    int4 v0 = *(int4*)p, v1 = *(int4*)(p + 8);
    unsigned short* s = (unsigned short*)&v0;
    unsigned short o[16];
    #pragma unroll
    for (int c = 0; c < 8; ++c)
        o[c] = f2bf(lrelu((bf2f(s[c]) - sst[2 * c]) * sst[2 * c + 1] * g[c] + be[c]));
    s = (unsigned short*)&v1;
    #pragma unroll
    for (int c = 0; c < 8; ++c)
        o[8 + c] = f2bf(lrelu((bf2f(s[c]) - sst[2 * (8 + c)]) * sst[2 * (8 + c) + 1] * g[8 + c] + be[8 + c]));
    *(int4*)p       = *(int4*)&o[0];
    *(int4*)(p + 8) = *(int4*)&o[8];
}

// BN2 finalize+apply in-place on bf16 NHWC [64][1024][32]. Grid exactly 256.
__global__ __launch_bounds__(256) void bn2_apply(unsigned short* __restrict__ xN,
                          const float2* __restrict__ part,
                          const float* __restrict__ g, const float* __restrict__ be)
{
    __shared__ float sst[64];
    int idx = blockIdx.x * blockDim.x + threadIdx.x;
    int f = idx >> 15;
    finalize_stats<32, 256>(part, f, 1.f / (32.f * 1024.f), sst);
    unsigned short* p = xN + (size_t)idx * 32;
    unsigned short o[32];
    #pragma unroll
    for (int q = 0; q < 4; ++q) {
        int4 v = *(int4*)(p + q * 8);
        unsigned short* s = (unsigned short*)&v;
        #pragma unroll
        for (int k = 0; k < 8; ++k) {
            int c = q * 8 + k;
            o[c] = f2bf(lrelu((bf2f(s[k]) - sst[2 * c]) * sst[2 * c + 1] * g[c] + be[c]));
        }
    }
    #pragma unroll
    for (int q = 0; q < 4; ++q) *(int4*)(p + q * 8) = *(int4*)&o[q * 8];
}

// BN3 finalize + lrelu + channel L2 norm: NHWC f32 -> NHWC f32. Grid exactly 256.
__global__ __launch_bounds__(256) void bn3_l2n_nhwc(const float* __restrict__ xN,
                             const float2* __restrict__ part,
                             const float* __restrict__ g, const float* __restrict__ be,
                             float* __restrict__ outN)
{
    __shared__ float sst[64];
    int idx = blockIdx.x * blockDim.x + threadIdx.x;
    int f = idx >> 15;
    finalize_stats<32, 128>(part, f, 1.f / (32.f * 1024.f), sst);
    const float* src = xN + (size_t)idx * 32;
    float v[32];
    float ss = 0.f;
    #pragma unroll
    for (int c = 0; c < 32; ++c) {
        float t = lrelu((src[c] - sst[2 * c]) * sst[2 * c + 1] * g[c] + be[c]);
        v[c] = t; ss += t * t;
    }
    float inv = 1.f / fmaxf(sqrtf(ss), 1e-12f);
    float* dst = outN + (size_t)idx * 32;
    #pragma unroll
    for (int c = 0; c < 32; ++c) dst[c] = v[c] * inv;
}

// ---------------------------------------------------------------------------
// Correlation (LDS-tiled): coarseN NHWC f32 -> cost bf16 [B][1024][192]
// ---------------------------------------------------------------------------
#define CSWZ(c, w) ((c) ^ (((w) & 7) << 2))

__global__ __launch_bounds__(256) void corr_tile(const float* __restrict__ xN,
                                                 unsigned short* __restrict__ cost)
{
    __shared__ float sA[32 * 32];
    __shared__ float sB[13][32 * 32];
    __shared__ unsigned short sC[32][176];

    const int h = blockIdx.x, b = blockIdx.y;
    const float* Ab = xN + ((size_t)b * 1024 + h * 32) * 32;
    const float* Bb = xN + ((size_t)(BATCH + b) * 1024) * 32;

    {
        int t = threadIdx.x;
        int w = t >> 3, gr = t & 7;
        f32x4 v = *(const f32x4*)&Ab[w * 32 + gr * 4];
        *(f32x4*)&sA[w * 32 + CSWZ(gr * 4, w)] = v;
    }
    for (int t = threadIdx.x; t < 13 * 256; t += 256) {
        int row = t >> 8, q = t & 255;
        int w = q >> 3, gr = q & 7;
        int gh = h + row - 6;
        f32x4 v = {0.f, 0.f, 0.f, 0.f};
        if ((unsigned)gh < 32u) v = *(const f32x4*)&Bb[((size_t)gh * 32 + w) * 32 + gr * 4];
        *(f32x4*)&sB[row][w * 32 + CSWZ(gr * 4, w)] = v;
    }
    __syncthreads();

    const int w = threadIdx.x & 31;
    const int g = threadIdx.x >> 5;
    f32x4 a[8];
    #pragma unroll
    for (int gr = 0; gr < 8; ++gr) a[gr] = *(const f32x4*)&sA[w * 32 + CSWZ(gr * 4, w)];

    for (int dy = g; dy < 13; dy += 8) {
        #pragma unroll
        for (int dx = 0; dx < 13; ++dx) {
            int wb = w + dx - 6;
            float s = 0.f;
            if ((unsigned)wb < 32u) {
                #pragma unroll
                for (int gr = 0; gr < 8; ++gr) {
                    f32x4 bv = *(const f32x4*)&sB[dy][wb * 32 + CSWZ(gr * 4, wb)];
                    s += a[gr].x * bv.x + a[gr].y * bv.y + a[gr].z * bv.z + a[gr].w * bv.w;
                }
            }
            sC[w][dy * 13 + dx] = f2bf(s);
        }
    }
    __syncthreads();

    for (int t = threadIdx.x; t < 32 * 169; t += 256) {
        int ww = t / 169;
        int d  = t - ww * 169;
        cost[((size_t)(b * 1024) + h * 32 + ww) * 192 + d] = sC[ww][d];
    }
}

// ---------------------------------------------------------------------------
extern "C" void kernel_launch(void* const* d_in, const int* in_sizes, int n_in,
                              void* d_out, int out_size, void* d_ws, size_t ws_size,
                              hipStream_t stream)
{
    const float* frameA = (const float*)d_in[0];
    const float* frameB = (const float*)d_in[1];
    const float* w1  = (const float*)d_in[2];
    const float* b1  = (const float*)d_in[3];
    const float* g1  = (const float*)d_in[4];
    const float* be1 = (const float*)d_in[5];
    const float* w2  = (const float*)d_in[6];
    const float* b2  = (const float*)d_in[7];
    const float* g2  = (const float*)d_in[8];
    const float* be2 = (const float*)d_in[9];
    const float* w3  = (const float*)d_in[10];
    const float* b3  = (const float*)d_in[11];
    const float* g3  = (const float*)d_in[12];
    const float* be3 = (const float*)d_in[13];
    const float* wc1 = (const float*)d_in[14];
    const float* bc1 = (const float*)d_in[15];
    const float* wc2 = (const float*)d_in[16];
    const float* bc2 = (const float*)d_in[17];
    const float* wf1 = (const float*)d_in[18];
    const float* bf1 = (const float*)d_in[19];
    const float* wf2 = (const float*)d_in[20];
    const float* bf2 = (const float*)d_in[21];
    const float* wo  = (const float*)d_in[22];
    const float* bo  = (const float*)d_in[23];

    // workspace layout
    float* ws      = (float*)d_ws;
    float* c3N     = ws;                    // [64][1024][32] f32   2,097,152
    float* coarseN = c3N + 2097152;         // [64][1024][32] f32   2,097,152
    float2* part   = (float2*)(coarseN + 2097152);    // 16384 float2 (BN2 needs (63)*256+255 max)
    unsigned short* fineN = (unsigned short*)(part + 16384);  // [64][64][64][16]  4,194,304
    unsigned short* h2bf  = fineN + 4194304;   // [64][32][32][32]  2,097,152
    unsigned short* costN = h2bf + 2097152;    // [B][32][32][192]  6,291,456
    unsigned short* d1    = costN + 6291456;   // [B][32][32][128]  4,194,304
    unsigned short* d2    = d1 + 4194304;      // [B][32][32][64]   2,097,152
    unsigned short* f1o   = d2 + 2097152;      // [B][64][64][64]   8,388,608
    unsigned short* wT1   = f1o + 8388608;     // [9][128][192]       221,184
    unsigned short* wT2   = wT1 + 221184;      // [9][64][128]         73,728
    unsigned short* wTf1  = wT2 + 73728;       // [9][64][96]          55,296
    unsigned short* wTf2  = wTf1 + 55296;      // [9][32][64]          18,432
    unsigned short* wE2   = wTf2 + 18432;      // [13][32][32]         13,312
    unsigned short* wE3   = wE2 + 13312;       // [9][32][32]           9,216

    const int T = 256;

    prep_w_all<<<cdiv(391168, T), T, 0, stream>>>(wc1, wc2, wf1, wf2, w2, w3,
                                                  wT1, wT2, wTf1, wTf2, wE2, wE3);

    // encoder layer 1: conv (bf16 out + partials) -> BN apply in place
    conv1_tiled<<<dim3(4, 2, 2 * BATCH), T, 0, stream>>>(frameA, frameB, w1, b1, fineN, part);
    bn1_apply<<<1024, T, 0, stream>>>(fineN, part, g1, be1);

    // encoder layer 2: MFMA conv (bf16 out + partials) -> BN apply in place
    conv2s_mfma<<<dim3(8, 1, 64), T, 0, stream>>>(fineN, wE2, b2, h2bf, part);
    bn2_apply<<<256, T, 0, stream>>>(h2bf, part, g2, be2);

    // encoder layer 3 (MFMA, f32 out) -> partials -> BN + L2-norm
    conv3x3_mfma<32, 32, 32, 8, 0, 1><<<dim3(8, 1, 64), T, 0, stream>>>(
        h2bf, nullptr, wE3, b3, (unsigned short*)c3N, nullptr, nullptr, nullptr);
    bn_part_nhwc<32, 128><<<2 * 128, T, 0, stream>>>(c3N, part, 1024);
    bn3_l2n_nhwc<<<256, T, 0, stream>>>(c3N, part, g3, be3, coarseN);

    // correlation (LDS-tiled) -> bf16 NHWC cost
    corr_tile<<<dim3(32, BATCH), T, 0, stream>>>(coarseN, costN);

    // decoder (bf16 MFMA, TH=8 everywhere except fused f2)
    conv3x3_mfma<192, 128, 32, 8, 0, 0><<<dim3(8, 2, BATCH), T, 0, stream>>>(
        costN, nullptr, wT1, bc1, d1, nullptr, nullptr, nullptr);
    conv3x3_mfma<128, 64, 32, 8, 0, 0><<<dim3(8, 1, BATCH), T, 0, stream>>>(
        d1, nullptr, wT2, bc2, d2, nullptr, nullptr, nullptr);
    conv3x3_mfma<96, 64, 64, 8, 1, 0><<<dim3(32, 1, BATCH), T, 0, stream>>>(
        d2, fineN, wTf1, bf1, f1o, nullptr, nullptr, nullptr);
    // f2 + fused 1x1 output conv -> d_out directly
    conv3x3_mfma<64, 32, 64, 16, 0, 2><<<dim3(16, 1, BATCH), T, 0, stream>>>(
        f1o, nullptr, wTf2, bf2, nullptr, (float*)d_out, wo, bo);
}